// Round 6
// baseline (540.749 us; speedup 1.0000x reference)
//
#include <hip/hip_runtime.h>

#define NN 50000
#define NE 800000
#define F  128
#define NB 2
#define M2 (NB * NN)   // 100000 fused rows, layout [node][batch][feat]

typedef __attribute__((ext_vector_type(8))) short     bf16x8;
typedef __attribute__((ext_vector_type(4))) float     f32x4;
typedef __attribute__((ext_vector_type(8))) unsigned short u16x8;
typedef __attribute__((ext_vector_type(4))) unsigned short u16x4;

__device__ inline unsigned short f2bf_rn(float f) {
    unsigned u = __float_as_uint(f);
    u += 0x7FFFu + ((u >> 16) & 1u);
    return (unsigned short)(u >> 16);
}
__device__ inline float bf2f(unsigned short h) {
    return __uint_as_float(((unsigned)h) << 16);
}

// ---------------- CSR build ----------------

__global__ void count_kernel(const int* __restrict__ dst, int* __restrict__ cnt) {
    int e = blockIdx.x * blockDim.x + threadIdx.x;
    if (e < NE) atomicAdd(&cnt[dst[e]], 1);
}

__global__ __launch_bounds__(1024) void scan1_kernel(const int* __restrict__ cnt,
                                                     int* __restrict__ local_ex,
                                                     int* __restrict__ blocksums) {
    __shared__ int sd[1024];
    int i = blockIdx.x * 1024 + threadIdx.x;
    int v = (i < NN) ? cnt[i] : 0;
    sd[threadIdx.x] = v;
    __syncthreads();
    for (int off = 1; off < 1024; off <<= 1) {
        int t = 0;
        if ((int)threadIdx.x >= off) t = sd[threadIdx.x - off];
        __syncthreads();
        sd[threadIdx.x] += t;
        __syncthreads();
    }
    if (i < NN) local_ex[i] = sd[threadIdx.x] - v;  // exclusive within block
    if (threadIdx.x == 1023) blocksums[blockIdx.x] = sd[1023];
}

__global__ void scan2_kernel(int* __restrict__ bs, int nb) {
    int lane = threadIdx.x;
    int v = (lane < nb) ? bs[lane] : 0;
    for (int off = 1; off < 64; off <<= 1) {
        int t = __shfl_up(v, off);
        if (lane >= off) v += t;
    }
    int ex = __shfl_up(v, 1);
    if (lane == 0) ex = 0;
    if (lane < nb) bs[lane] = ex;
}

__global__ void scan3_kernel(const int* __restrict__ local_ex, const int* __restrict__ bs,
                             const int* __restrict__ cnt,
                             int* __restrict__ rowptr, float* __restrict__ dinv) {
    int i = blockIdx.x * blockDim.x + threadIdx.x;
    if (i < NN) {
        rowptr[i] = local_ex[i] + bs[i >> 10];
        int d = cnt[i];
        dinv[i] = (d > 0) ? 1.0f / (float)d : 0.0f;
    }
    if (i == 0) rowptr[NN] = NE;
}

__global__ void fill_kernel(const int* __restrict__ src, const int* __restrict__ dst,
                            const int* __restrict__ rowptr, int* __restrict__ cursor,
                            int* __restrict__ eidx) {
    int e = blockIdx.x * blockDim.x + threadIdx.x;
    if (e < NE) {
        int d = dst[e];
        int p = rowptr[d] + atomicAdd(&cursor[d], 1);
        __builtin_nontemporal_store(src[e], &eidx[p]);  // scattered 4B: skip write-allocate
    }
}

// ---------------- weight split (all 3 layers) ----------------

__global__ void wsplit_kernel(const float* __restrict__ Ws0, const float* __restrict__ Wn0,
                              const float* __restrict__ Ws1, const float* __restrict__ Wn1,
                              const float* __restrict__ Ws2, const float* __restrict__ Wn2,
                              unsigned short* __restrict__ hi, unsigned short* __restrict__ lo) {
    int idx = blockIdx.x * blockDim.x + threadIdx.x;  // 3*128*256
    int l = idx >> 15;
    int r = idx & 32767;
    int j = r >> 8, k = r & 255;
    const float* Ws = (l == 0) ? Ws0 : (l == 1) ? Ws1 : Ws2;
    const float* Wn = (l == 0) ? Wn0 : (l == 1) ? Wn1 : Wn2;
    float v = (k < 128) ? Ws[j * 128 + k] : Wn[j * 128 + (k - 128)];
    unsigned short h = f2bf_rn(v);
    hi[idx] = h;
    lo[idx] = f2bf_rn(v - bf2f(h));
}

// ---------------- x split: [b][n][f] fp32 -> [n][b][f] hi/lo bf16 ----------------

__global__ void xsplit_kernel(const float* __restrict__ x,
                              unsigned short* __restrict__ hi, unsigned short* __restrict__ lo) {
    size_t idx = (size_t)blockIdx.x * blockDim.x + threadIdx.x;  // NB*NN*F/4 threads
    float4 v = *reinterpret_cast<const float4*>(&x[idx * 4]);
    int f4 = (int)(idx & 31);                 // F/4 = 32 float4s per row
    size_t row = idx >> 5;                    // b*NN + n
    int b = (row >= NN) ? 1 : 0;
    size_t n = row - (size_t)b * NN;
    size_t o = ((n << 1) + b) * F + f4 * 4;   // interleaved row n*2+b
    u16x4 h4, l4;
    float vv[4] = {v.x, v.y, v.z, v.w};
#pragma unroll
    for (int i = 0; i < 4; ++i) {
        unsigned short h = f2bf_rn(vv[i]);
        h4[i] = h;
        l4[i] = f2bf_rn(vv[i] - bf2f(h));
    }
    *reinterpret_cast<u16x4*>(&hi[o]) = h4;
    *reinterpret_cast<u16x4*>(&lo[o]) = l4;
}

// ---------------- mean aggregation: 1 wave/node, both batches per edge ----------------
// h layout [node][2][128] bf16 -> one edge = one contiguous 512B row read (32 lanes x 16B).
// 2 lane-groups x unroll 4 = 8 edge-rows in flight per wave.

__global__ void aggregate_bf16(const unsigned short* __restrict__ h,
                               const int* __restrict__ rowptr, const int* __restrict__ eidx,
                               const float* __restrict__ dinv,
                               unsigned short* __restrict__ agg_hi, unsigned short* __restrict__ agg_lo) {
    int gtid = blockIdx.x * blockDim.x + threadIdx.x;
    int node = gtid >> 6;
    int lane = gtid & 63;
    if (node >= NN) return;
    int g = lane >> 5, li = lane & 31;
    int s0 = rowptr[node], s1 = rowptr[node + 1];

    float acc[8] = {0.f, 0.f, 0.f, 0.f, 0.f, 0.f, 0.f, 0.f};

    for (int e = s0; e < s1; e += 8) {
        int sidx[4];
        u16x8 vv[4];
#pragma unroll
        for (int j = 0; j < 4; ++j) {
            int ee = e + 2 * j + g;
            sidx[j] = (ee < s1) ? eidx[ee] : -1;
        }
#pragma unroll
        for (int j = 0; j < 4; ++j)
            if (sidx[j] >= 0)
                vv[j] = *reinterpret_cast<const u16x8*>(&h[(size_t)sidx[j] * 256 + li * 8]);
#pragma unroll
        for (int j = 0; j < 4; ++j)
            if (sidx[j] >= 0) {
#pragma unroll
                for (int i = 0; i < 8; ++i) acc[i] += bf2f(vv[j][i]);
            }
    }

#pragma unroll
    for (int i = 0; i < 8; ++i) acc[i] += __shfl_xor(acc[i], 32);

    if (g == 0) {
        float di = dinv[node];
        u16x8 h8, l8;
#pragma unroll
        for (int i = 0; i < 8; ++i) {
            float v = acc[i] * di;
            unsigned short hh = f2bf_rn(v);
            h8[i] = hh;
            l8[i] = f2bf_rn(v - bf2f(hh));
        }
        *reinterpret_cast<u16x8*>(&agg_hi[(size_t)node * 256 + li * 8]) = h8;
        *reinterpret_cast<u16x8*>(&agg_lo[(size_t)node * 256 + li * 8]) = l8;
    }
}

// ---------------- MFMA GEMM over M2=100000 interleaved rows ----------------
// Block: 64 rows x 128 cols, 4 waves 2x2; wave = 32 rows x 64 cols (2x4 frags of 16x16x32).
// Small tile -> 1563 blocks, ~24 waves/CU; acc = 32 VGPR -> deep load pipelining.

__global__ __launch_bounds__(256) void sage_gemm_mfma(
    const unsigned short* __restrict__ Shi, const unsigned short* __restrict__ Slo,
    const unsigned short* __restrict__ Ghi, const unsigned short* __restrict__ Glo,
    const unsigned short* __restrict__ Whi, const unsigned short* __restrict__ Wlo,
    const float* __restrict__ bias,
    float* __restrict__ outf, unsigned short* __restrict__ ohi, unsigned short* __restrict__ olo,
    int final_layer)
{
    int tid = threadIdx.x;
    int lane = tid & 63, wave = tid >> 6;
    int wm = wave >> 1, wn = wave & 1;
    int l15 = lane & 15, kg = lane >> 4;
    int row_base = blockIdx.x * 64 + wm * 32;
    int col_base = wn * 64;

    f32x4 acc[2][4];
#pragma unroll
    for (int m = 0; m < 2; ++m)
#pragma unroll
        for (int n = 0; n < 4; ++n) acc[m][n] = (f32x4){0.f, 0.f, 0.f, 0.f};

    int arow[2];
#pragma unroll
    for (int m = 0; m < 2; ++m) arow[m] = min(row_base + m * 16 + l15, M2 - 1);
    int bcol[4];
    float bv[4];
#pragma unroll
    for (int n = 0; n < 4; ++n) {
        bcol[n] = col_base + n * 16 + l15;
        bv[n] = bias[bcol[n]];
    }

#pragma unroll
    for (int ks = 0; ks < 8; ++ks) {
        const unsigned short* Ahi = (ks < 4) ? Shi : Ghi;
        const unsigned short* Alo = (ks < 4) ? Slo : Glo;
        int ka = (ks & 3) * 32 + kg * 8;
        int kb = ks * 32 + kg * 8;

        bf16x8 ah[2], al[2], bh[4], bl[4];
#pragma unroll
        for (int m = 0; m < 2; ++m) {
            size_t off = (size_t)arow[m] * F + ka;
            ah[m] = *reinterpret_cast<const bf16x8*>(&Ahi[off]);
            al[m] = *reinterpret_cast<const bf16x8*>(&Alo[off]);
        }
#pragma unroll
        for (int n = 0; n < 4; ++n) {
            size_t off = (size_t)bcol[n] * 256 + kb;
            bh[n] = *reinterpret_cast<const bf16x8*>(&Whi[off]);
            bl[n] = *reinterpret_cast<const bf16x8*>(&Wlo[off]);
        }

#pragma unroll
        for (int m = 0; m < 2; ++m)
#pragma unroll
            for (int n = 0; n < 4; ++n) {
                acc[m][n] = __builtin_amdgcn_mfma_f32_16x16x32_bf16(ah[m], bh[n], acc[m][n], 0, 0, 0);
                acc[m][n] = __builtin_amdgcn_mfma_f32_16x16x32_bf16(ah[m], bl[n], acc[m][n], 0, 0, 0);
                acc[m][n] = __builtin_amdgcn_mfma_f32_16x16x32_bf16(al[m], bh[n], acc[m][n], 0, 0, 0);
            }
    }

    // epilogue: C frag col=lane&15, row=(lane>>4)*4+i
#pragma unroll
    for (int m = 0; m < 2; ++m) {
#pragma unroll
        for (int i = 0; i < 4; ++i) {
            int r = row_base + m * 16 + kg * 4 + i;
            if (r < M2) {
#pragma unroll
                for (int n = 0; n < 4; ++n) {
                    float v = fmaxf(acc[m][n][i] + bv[n], 0.f);
                    if (final_layer) {
                        // r = node*2 + b  ->  out[b][node][col]
                        size_t off = ((size_t)(r & 1) * NN + (size_t)(r >> 1)) * F + bcol[n];
                        outf[off] = v;
                    } else {
                        size_t off = (size_t)r * F + bcol[n];
                        unsigned short hh = f2bf_rn(v);
                        ohi[off] = hh;
                        olo[off] = f2bf_rn(v - bf2f(hh));
                    }
                }
            }
        }
    }
}

// ---------------- launcher ----------------

extern "C" void kernel_launch(void* const* d_in, const int* in_sizes, int n_in,
                              void* d_out, int out_size, void* d_ws, size_t ws_size,
                              hipStream_t stream) {
    const float* x  = (const float*)d_in[0];
    const int* src  = (const int*)d_in[1];
    const int* dst  = (const int*)d_in[2];
    const float* Wp[3][2] = {
        {(const float*)d_in[3], (const float*)d_in[4]},
        {(const float*)d_in[6], (const float*)d_in[7]},
        {(const float*)d_in[9], (const float*)d_in[10]},
    };
    const float* bp[3] = {(const float*)d_in[5], (const float*)d_in[8], (const float*)d_in[11]};
    float* out = (float*)d_out;

    char* p = (char*)d_ws;
    auto alloc = [&](size_t b) -> void* {
        void* r = (void*)p;
        p += (b + 255) & ~(size_t)255;
        return r;
    };
    int* cnt      = (int*)alloc(sizeof(int) * NN);
    int* cursor   = (int*)alloc(sizeof(int) * NN);
    int* rowptr   = (int*)alloc(sizeof(int) * (NN + 1));
    int* local_ex = (int*)alloc(sizeof(int) * NN);
    int* bsums    = (int*)alloc(sizeof(int) * 64);
    int* eidx     = (int*)alloc(sizeof(int) * NE);
    float* dinv   = (float*)alloc(sizeof(float) * NN);
    unsigned short* Whi = (unsigned short*)alloc(sizeof(short) * 3 * 128 * 256);
    unsigned short* Wlo = (unsigned short*)alloc(sizeof(short) * 3 * 128 * 256);
    // interleaved feature buffers [node][batch][feat], ping-pong X <-> Y, agg G
    unsigned short* Xhi = (unsigned short*)alloc(sizeof(short) * M2 * F);
    unsigned short* Xlo = (unsigned short*)alloc(sizeof(short) * M2 * F);
    unsigned short* Yhi = (unsigned short*)alloc(sizeof(short) * M2 * F);
    unsigned short* Ylo = (unsigned short*)alloc(sizeof(short) * M2 * F);
    unsigned short* Ghi = (unsigned short*)alloc(sizeof(short) * M2 * F);
    unsigned short* Glo = (unsigned short*)alloc(sizeof(short) * M2 * F);

    hipMemsetAsync(cnt, 0, (char*)rowptr - (char*)cnt, stream);  // cnt + cursor

    count_kernel<<<(NE + 255) / 256, 256, 0, stream>>>(dst, cnt);
    const int NSB = (NN + 1023) / 1024;  // 49
    scan1_kernel<<<NSB, 1024, 0, stream>>>(cnt, local_ex, bsums);
    scan2_kernel<<<1, 64, 0, stream>>>(bsums, NSB);
    scan3_kernel<<<(NN + 255) / 256, 256, 0, stream>>>(local_ex, bsums, cnt, rowptr, dinv);
    fill_kernel<<<(NE + 255) / 256, 256, 0, stream>>>(src, dst, rowptr, cursor, eidx);

    wsplit_kernel<<<3 * 128, 256, 0, stream>>>(Wp[0][0], Wp[0][1], Wp[1][0], Wp[1][1],
                                               Wp[2][0], Wp[2][1], Whi, Wlo);

    xsplit_kernel<<<((size_t)NB * NN * F / 4) / 256, 256, 0, stream>>>(x, Xhi, Xlo);

    const int AGG_BLOCKS  = (NN * 64) / 256;        // 12500
    const int GEMM_BLOCKS = (M2 + 63) / 64;         // 1563

    // layer 1: X -> Y
    aggregate_bf16<<<AGG_BLOCKS, 256, 0, stream>>>(Xhi, rowptr, eidx, dinv, Ghi, Glo);
    sage_gemm_mfma<<<GEMM_BLOCKS, 256, 0, stream>>>(Xhi, Xlo, Ghi, Glo,
                                                    Whi + 0 * 32768, Wlo + 0 * 32768, bp[0],
                                                    nullptr, Yhi, Ylo, 0);
    // layer 2: Y -> X
    aggregate_bf16<<<AGG_BLOCKS, 256, 0, stream>>>(Yhi, rowptr, eidx, dinv, Ghi, Glo);
    sage_gemm_mfma<<<GEMM_BLOCKS, 256, 0, stream>>>(Yhi, Ylo, Ghi, Glo,
                                                    Whi + 1 * 32768, Wlo + 1 * 32768, bp[1],
                                                    nullptr, Xhi, Xlo, 0);
    // layer 3: X -> out
    aggregate_bf16<<<AGG_BLOCKS, 256, 0, stream>>>(Xhi, rowptr, eidx, dinv, Ghi, Glo);
    sage_gemm_mfma<<<GEMM_BLOCKS, 256, 0, stream>>>(Xhi, Xlo, Ghi, Glo,
                                                    Whi + 2 * 32768, Wlo + 2 * 32768, bp[2],
                                                    out, nullptr, nullptr, 1);
}

// Round 7
// 533.952 us; speedup vs baseline: 1.0127x; 1.0127x over previous
//
#include <hip/hip_runtime.h>

#define NN 50000
#define NE 800000
#define F  128
#define NB 2
#define M2 (NB * NN)   // 100000 fused rows, layout [node][batch][feat]

typedef __attribute__((ext_vector_type(8))) short     bf16x8;
typedef __attribute__((ext_vector_type(4))) float     f32x4;
typedef __attribute__((ext_vector_type(8))) unsigned short u16x8;
typedef __attribute__((ext_vector_type(4))) unsigned short u16x4;

__device__ inline unsigned short f2bf_rn(float f) {
    unsigned u = __float_as_uint(f);
    u += 0x7FFFu + ((u >> 16) & 1u);
    return (unsigned short)(u >> 16);
}
__device__ inline float bf2f(unsigned short h) {
    return __uint_as_float(((unsigned)h) << 16);
}

// ---------------- CSR build ----------------

__global__ void count_kernel(const int* __restrict__ dst, int* __restrict__ cnt) {
    int e = blockIdx.x * blockDim.x + threadIdx.x;
    if (e < NE) atomicAdd(&cnt[dst[e]], 1);
}

__global__ __launch_bounds__(1024) void scan1_kernel(const int* __restrict__ cnt,
                                                     int* __restrict__ local_ex,
                                                     int* __restrict__ blocksums) {
    __shared__ int sd[1024];
    int i = blockIdx.x * 1024 + threadIdx.x;
    int v = (i < NN) ? cnt[i] : 0;
    sd[threadIdx.x] = v;
    __syncthreads();
    for (int off = 1; off < 1024; off <<= 1) {
        int t = 0;
        if ((int)threadIdx.x >= off) t = sd[threadIdx.x - off];
        __syncthreads();
        sd[threadIdx.x] += t;
        __syncthreads();
    }
    if (i < NN) local_ex[i] = sd[threadIdx.x] - v;  // exclusive within block
    if (threadIdx.x == 1023) blocksums[blockIdx.x] = sd[1023];
}

__global__ void scan2_kernel(int* __restrict__ bs, int nb) {
    int lane = threadIdx.x;
    int v = (lane < nb) ? bs[lane] : 0;
    for (int off = 1; off < 64; off <<= 1) {
        int t = __shfl_up(v, off);
        if (lane >= off) v += t;
    }
    int ex = __shfl_up(v, 1);
    if (lane == 0) ex = 0;
    if (lane < nb) bs[lane] = ex;
}

__global__ void scan3_kernel(const int* __restrict__ local_ex, const int* __restrict__ bs,
                             const int* __restrict__ cnt,
                             int* __restrict__ rowptr, float* __restrict__ dinv) {
    int i = blockIdx.x * blockDim.x + threadIdx.x;
    if (i < NN) {
        rowptr[i] = local_ex[i] + bs[i >> 10];
        int d = cnt[i];
        dinv[i] = (d > 0) ? 1.0f / (float)d : 0.0f;
    }
    if (i == 0) rowptr[NN] = NE;
}

__global__ void fill_kernel(const int* __restrict__ src, const int* __restrict__ dst,
                            const int* __restrict__ rowptr, int* __restrict__ cursor,
                            int* __restrict__ eidx) {
    int e = blockIdx.x * blockDim.x + threadIdx.x;
    if (e < NE) {
        int d = dst[e];
        int p = rowptr[d] + atomicAdd(&cursor[d], 1);
        __builtin_nontemporal_store(src[e], &eidx[p]);  // scattered 4B: skip write-allocate
    }
}

// ---------------- weight split (all 3 layers) ----------------

__global__ void wsplit_kernel(const float* __restrict__ Ws0, const float* __restrict__ Wn0,
                              const float* __restrict__ Ws1, const float* __restrict__ Wn1,
                              const float* __restrict__ Ws2, const float* __restrict__ Wn2,
                              unsigned short* __restrict__ hi, unsigned short* __restrict__ lo) {
    int idx = blockIdx.x * blockDim.x + threadIdx.x;  // 3*128*256
    int l = idx >> 15;
    int r = idx & 32767;
    int j = r >> 8, k = r & 255;
    const float* Ws = (l == 0) ? Ws0 : (l == 1) ? Ws1 : Ws2;
    const float* Wn = (l == 0) ? Wn0 : (l == 1) ? Wn1 : Wn2;
    float v = (k < 128) ? Ws[j * 128 + k] : Wn[j * 128 + (k - 128)];
    unsigned short h = f2bf_rn(v);
    hi[idx] = h;
    lo[idx] = f2bf_rn(v - bf2f(h));
}

// ---------------- x split: [b][n][f] fp32 -> [n][b][f] hi/lo bf16 ----------------

__global__ void xsplit_kernel(const float* __restrict__ x,
                              unsigned short* __restrict__ hi, unsigned short* __restrict__ lo) {
    size_t idx = (size_t)blockIdx.x * blockDim.x + threadIdx.x;  // NB*NN*F/4 threads
    float4 v = *reinterpret_cast<const float4*>(&x[idx * 4]);
    int f4 = (int)(idx & 31);                 // F/4 = 32 float4s per row
    size_t row = idx >> 5;                    // b*NN + n
    int b = (row >= NN) ? 1 : 0;
    size_t n = row - (size_t)b * NN;
    size_t o = ((n << 1) + b) * F + f4 * 4;   // interleaved row n*2+b
    u16x4 h4, l4;
    float vv[4] = {v.x, v.y, v.z, v.w};
#pragma unroll
    for (int i = 0; i < 4; ++i) {
        unsigned short h = f2bf_rn(vv[i]);
        h4[i] = h;
        l4[i] = f2bf_rn(vv[i] - bf2f(h));
    }
    *reinterpret_cast<u16x4*>(&hi[o]) = h4;
    *reinterpret_cast<u16x4*>(&lo[o]) = l4;
}

// ---------------- mean aggregation: 1 wave/node, both batches per edge ----------------
// h layout [node][2][128] bf16 -> one edge = one contiguous 512B row read (32 lanes x 16B).
// 2 lane-groups x unroll 4 = 8 edge-rows in flight per wave.

__global__ void aggregate_bf16(const unsigned short* __restrict__ h,
                               const int* __restrict__ rowptr, const int* __restrict__ eidx,
                               const float* __restrict__ dinv,
                               unsigned short* __restrict__ agg_hi, unsigned short* __restrict__ agg_lo) {
    int gtid = blockIdx.x * blockDim.x + threadIdx.x;
    int node = gtid >> 6;
    int lane = gtid & 63;
    if (node >= NN) return;
    int g = lane >> 5, li = lane & 31;
    int s0 = rowptr[node], s1 = rowptr[node + 1];

    float acc[8] = {0.f, 0.f, 0.f, 0.f, 0.f, 0.f, 0.f, 0.f};

    for (int e = s0; e < s1; e += 8) {
        int sidx[4];
        u16x8 vv[4];
#pragma unroll
        for (int j = 0; j < 4; ++j) {
            int ee = e + 2 * j + g;
            sidx[j] = (ee < s1) ? eidx[ee] : -1;
        }
#pragma unroll
        for (int j = 0; j < 4; ++j)
            if (sidx[j] >= 0)
                vv[j] = *reinterpret_cast<const u16x8*>(&h[(size_t)sidx[j] * 256 + li * 8]);
#pragma unroll
        for (int j = 0; j < 4; ++j)
            if (sidx[j] >= 0) {
#pragma unroll
                for (int i = 0; i < 8; ++i) acc[i] += bf2f(vv[j][i]);
            }
    }

#pragma unroll
    for (int i = 0; i < 8; ++i) acc[i] += __shfl_xor(acc[i], 32);

    if (g == 0) {
        float di = dinv[node];
        u16x8 h8, l8;
#pragma unroll
        for (int i = 0; i < 8; ++i) {
            float v = acc[i] * di;
            unsigned short hh = f2bf_rn(v);
            h8[i] = hh;
            l8[i] = f2bf_rn(v - bf2f(hh));
        }
        *reinterpret_cast<u16x8*>(&agg_hi[(size_t)node * 256 + li * 8]) = h8;
        *reinterpret_cast<u16x8*>(&agg_lo[(size_t)node * 256 + li * 8]) = l8;
    }
}

// ---------------- MFMA GEMM over M2=100000 interleaved rows ----------------
// Block: 128 rows x 128 cols, 4 waves 2x2; wave = 64x64 (4x4 frags of 16x16x32).
// Explicit 2-stage register pipeline: stage k+2 loads issued before stage k MFMAs.
// __launch_bounds__(256,2): ~2 blocks/CU, lets allocator keep both stages resident.

__global__ __launch_bounds__(256, 2) void sage_gemm_mfma(
    const unsigned short* __restrict__ Shi, const unsigned short* __restrict__ Slo,
    const unsigned short* __restrict__ Ghi, const unsigned short* __restrict__ Glo,
    const unsigned short* __restrict__ Whi, const unsigned short* __restrict__ Wlo,
    const float* __restrict__ bias,
    float* __restrict__ outf, unsigned short* __restrict__ ohi, unsigned short* __restrict__ olo,
    int final_layer)
{
    int tid = threadIdx.x;
    int lane = tid & 63, wave = tid >> 6;
    int wm = wave >> 1, wn = wave & 1;
    int l15 = lane & 15, kg = lane >> 4;
    int row_base = blockIdx.x * 128 + wm * 64;
    int col_base = wn * 64;

    f32x4 acc[4][4];
#pragma unroll
    for (int m = 0; m < 4; ++m)
#pragma unroll
        for (int n = 0; n < 4; ++n) acc[m][n] = (f32x4){0.f, 0.f, 0.f, 0.f};

    int arow[4];
#pragma unroll
    for (int m = 0; m < 4; ++m) arow[m] = min(row_base + m * 16 + l15, M2 - 1);
    int bcol[4];
    float bv[4];
#pragma unroll
    for (int n = 0; n < 4; ++n) {
        bcol[n] = col_base + n * 16 + l15;
        bv[n] = bias[bcol[n]];
    }

    auto loadA = [&](bf16x8* ah, bf16x8* al,
                     const unsigned short* Hi, const unsigned short* Lo, int kc) {
#pragma unroll
        for (int m = 0; m < 4; ++m) {
            size_t off = (size_t)arow[m] * F + kc;
            ah[m] = *reinterpret_cast<const bf16x8*>(&Hi[off]);
            al[m] = *reinterpret_cast<const bf16x8*>(&Lo[off]);
        }
    };
    auto loadB = [&](bf16x8* bh, bf16x8* bl, int kb) {
#pragma unroll
        for (int n = 0; n < 4; ++n) {
            size_t off = (size_t)bcol[n] * 256 + kb;
            bh[n] = *reinterpret_cast<const bf16x8*>(&Whi[off]);
            bl[n] = *reinterpret_cast<const bf16x8*>(&Wlo[off]);
        }
    };
    auto mm = [&](bf16x8* ah, bf16x8* al, bf16x8* bh, bf16x8* bl) {
#pragma unroll
        for (int m = 0; m < 4; ++m)
#pragma unroll
            for (int n = 0; n < 4; ++n) {
                acc[m][n] = __builtin_amdgcn_mfma_f32_16x16x32_bf16(ah[m], bh[n], acc[m][n], 0, 0, 0);
                acc[m][n] = __builtin_amdgcn_mfma_f32_16x16x32_bf16(ah[m], bl[n], acc[m][n], 0, 0, 0);
                acc[m][n] = __builtin_amdgcn_mfma_f32_16x16x32_bf16(al[m], bh[n], acc[m][n], 0, 0, 0);
            }
    };

    bf16x8 Ah0[4], Al0[4], Bh0[4], Bl0[4];
    bf16x8 Ah1[4], Al1[4], Bh1[4], Bl1[4];
    int kc = kg * 8;

    loadA(Ah0, Al0, Shi, Slo, kc);        loadB(Bh0, Bl0, kc);          // ks0
    loadA(Ah1, Al1, Shi, Slo, 32 + kc);   loadB(Bh1, Bl1, 32 + kc);     // ks1
    mm(Ah0, Al0, Bh0, Bl0);                                             // ks0
    loadA(Ah0, Al0, Shi, Slo, 64 + kc);   loadB(Bh0, Bl0, 64 + kc);     // ks2
    mm(Ah1, Al1, Bh1, Bl1);                                             // ks1
    loadA(Ah1, Al1, Shi, Slo, 96 + kc);   loadB(Bh1, Bl1, 96 + kc);     // ks3
    mm(Ah0, Al0, Bh0, Bl0);                                             // ks2
    loadA(Ah0, Al0, Ghi, Glo, kc);        loadB(Bh0, Bl0, 128 + kc);    // ks4
    mm(Ah1, Al1, Bh1, Bl1);                                             // ks3
    loadA(Ah1, Al1, Ghi, Glo, 32 + kc);   loadB(Bh1, Bl1, 160 + kc);    // ks5
    mm(Ah0, Al0, Bh0, Bl0);                                             // ks4
    loadA(Ah0, Al0, Ghi, Glo, 64 + kc);   loadB(Bh0, Bl0, 192 + kc);    // ks6
    mm(Ah1, Al1, Bh1, Bl1);                                             // ks5
    loadA(Ah1, Al1, Ghi, Glo, 96 + kc);   loadB(Bh1, Bl1, 224 + kc);    // ks7
    mm(Ah0, Al0, Bh0, Bl0);                                             // ks6
    mm(Ah1, Al1, Bh1, Bl1);                                             // ks7

    // epilogue: C frag col=lane&15, row=(lane>>4)*4+i
#pragma unroll
    for (int m = 0; m < 4; ++m) {
#pragma unroll
        for (int i = 0; i < 4; ++i) {
            int r = row_base + m * 16 + kg * 4 + i;
            if (r < M2) {
#pragma unroll
                for (int n = 0; n < 4; ++n) {
                    float v = fmaxf(acc[m][n][i] + bv[n], 0.f);
                    if (final_layer) {
                        // r = node*2 + b  ->  out[b][node][col]
                        size_t off = ((size_t)(r & 1) * NN + (size_t)(r >> 1)) * F + bcol[n];
                        outf[off] = v;
                    } else {
                        size_t off = (size_t)r * F + bcol[n];
                        unsigned short hh = f2bf_rn(v);
                        ohi[off] = hh;
                        olo[off] = f2bf_rn(v - bf2f(hh));
                    }
                }
            }
        }
    }
}

// ---------------- launcher ----------------

extern "C" void kernel_launch(void* const* d_in, const int* in_sizes, int n_in,
                              void* d_out, int out_size, void* d_ws, size_t ws_size,
                              hipStream_t stream) {
    const float* x  = (const float*)d_in[0];
    const int* src  = (const int*)d_in[1];
    const int* dst  = (const int*)d_in[2];
    const float* Wp[3][2] = {
        {(const float*)d_in[3], (const float*)d_in[4]},
        {(const float*)d_in[6], (const float*)d_in[7]},
        {(const float*)d_in[9], (const float*)d_in[10]},
    };
    const float* bp[3] = {(const float*)d_in[5], (const float*)d_in[8], (const float*)d_in[11]};
    float* out = (float*)d_out;

    char* p = (char*)d_ws;
    auto alloc = [&](size_t b) -> void* {
        void* r = (void*)p;
        p += (b + 255) & ~(size_t)255;
        return r;
    };
    int* cnt      = (int*)alloc(sizeof(int) * NN);
    int* cursor   = (int*)alloc(sizeof(int) * NN);
    int* rowptr   = (int*)alloc(sizeof(int) * (NN + 1));
    int* local_ex = (int*)alloc(sizeof(int) * NN);
    int* bsums    = (int*)alloc(sizeof(int) * 64);
    int* eidx     = (int*)alloc(sizeof(int) * NE);
    float* dinv   = (float*)alloc(sizeof(float) * NN);
    unsigned short* Whi = (unsigned short*)alloc(sizeof(short) * 3 * 128 * 256);
    unsigned short* Wlo = (unsigned short*)alloc(sizeof(short) * 3 * 128 * 256);
    // interleaved feature buffers [node][batch][feat], ping-pong X <-> Y, agg G
    unsigned short* Xhi = (unsigned short*)alloc(sizeof(short) * M2 * F);
    unsigned short* Xlo = (unsigned short*)alloc(sizeof(short) * M2 * F);
    unsigned short* Yhi = (unsigned short*)alloc(sizeof(short) * M2 * F);
    unsigned short* Ylo = (unsigned short*)alloc(sizeof(short) * M2 * F);
    unsigned short* Ghi = (unsigned short*)alloc(sizeof(short) * M2 * F);
    unsigned short* Glo = (unsigned short*)alloc(sizeof(short) * M2 * F);

    hipMemsetAsync(cnt, 0, (char*)rowptr - (char*)cnt, stream);  // cnt + cursor

    count_kernel<<<(NE + 255) / 256, 256, 0, stream>>>(dst, cnt);
    const int NSB = (NN + 1023) / 1024;  // 49
    scan1_kernel<<<NSB, 1024, 0, stream>>>(cnt, local_ex, bsums);
    scan2_kernel<<<1, 64, 0, stream>>>(bsums, NSB);
    scan3_kernel<<<(NN + 255) / 256, 256, 0, stream>>>(local_ex, bsums, cnt, rowptr, dinv);
    fill_kernel<<<(NE + 255) / 256, 256, 0, stream>>>(src, dst, rowptr, cursor, eidx);

    wsplit_kernel<<<3 * 128, 256, 0, stream>>>(Wp[0][0], Wp[0][1], Wp[1][0], Wp[1][1],
                                               Wp[2][0], Wp[2][1], Whi, Wlo);

    xsplit_kernel<<<((size_t)NB * NN * F / 4) / 256, 256, 0, stream>>>(x, Xhi, Xlo);

    const int AGG_BLOCKS  = (NN * 64) / 256;        // 12500
    const int GEMM_BLOCKS = (M2 + 127) / 128;       // 782

    // layer 1: X -> Y
    aggregate_bf16<<<AGG_BLOCKS, 256, 0, stream>>>(Xhi, rowptr, eidx, dinv, Ghi, Glo);
    sage_gemm_mfma<<<GEMM_BLOCKS, 256, 0, stream>>>(Xhi, Xlo, Ghi, Glo,
                                                    Whi + 0 * 32768, Wlo + 0 * 32768, bp[0],
                                                    nullptr, Yhi, Ylo, 0);
    // layer 2: Y -> X
    aggregate_bf16<<<AGG_BLOCKS, 256, 0, stream>>>(Yhi, rowptr, eidx, dinv, Ghi, Glo);
    sage_gemm_mfma<<<GEMM_BLOCKS, 256, 0, stream>>>(Yhi, Ylo, Ghi, Glo,
                                                    Whi + 1 * 32768, Wlo + 1 * 32768, bp[1],
                                                    nullptr, Xhi, Xlo, 0);
    // layer 3: X -> out
    aggregate_bf16<<<AGG_BLOCKS, 256, 0, stream>>>(Xhi, rowptr, eidx, dinv, Ghi, Glo);
    sage_gemm_mfma<<<GEMM_BLOCKS, 256, 0, stream>>>(Xhi, Xlo, Ghi, Glo,
                                                    Whi + 2 * 32768, Wlo + 2 * 32768, bp[2],
                                                    out, nullptr, nullptr, 1);
}

// Round 8
// 411.052 us; speedup vs baseline: 1.3155x; 1.2990x over previous
//
#include <hip/hip_runtime.h>

#define NN 50000
#define NE 800000
#define F  128
#define NB 2
#define M2 (NB * NN)   // 100000 fused rows, layout [node][batch][feat]

typedef __attribute__((ext_vector_type(8))) short     bf16x8;
typedef __attribute__((ext_vector_type(4))) float     f32x4;
typedef __attribute__((ext_vector_type(8))) unsigned short u16x8;
typedef __attribute__((ext_vector_type(4))) unsigned short u16x4;

__device__ inline unsigned short f2bf_rn(float f) {
    unsigned u = __float_as_uint(f);
    u += 0x7FFFu + ((u >> 16) & 1u);
    return (unsigned short)(u >> 16);
}
__device__ inline float bf2f(unsigned short h) {
    return __uint_as_float(((unsigned)h) << 16);
}

// ---------------- CSR build ----------------

__global__ void count_kernel(const int* __restrict__ dst, int* __restrict__ cnt) {
    int e = blockIdx.x * blockDim.x + threadIdx.x;
    if (e < NE) atomicAdd(&cnt[dst[e]], 1);
}

__global__ __launch_bounds__(1024) void scan1_kernel(const int* __restrict__ cnt,
                                                     int* __restrict__ local_ex,
                                                     int* __restrict__ blocksums) {
    __shared__ int sd[1024];
    int i = blockIdx.x * 1024 + threadIdx.x;
    int v = (i < NN) ? cnt[i] : 0;
    sd[threadIdx.x] = v;
    __syncthreads();
    for (int off = 1; off < 1024; off <<= 1) {
        int t = 0;
        if ((int)threadIdx.x >= off) t = sd[threadIdx.x - off];
        __syncthreads();
        sd[threadIdx.x] += t;
        __syncthreads();
    }
    if (i < NN) local_ex[i] = sd[threadIdx.x] - v;  // exclusive within block
    if (threadIdx.x == 1023) blocksums[blockIdx.x] = sd[1023];
}

__global__ void scan2_kernel(int* __restrict__ bs, int nb) {
    int lane = threadIdx.x;
    int v = (lane < nb) ? bs[lane] : 0;
    for (int off = 1; off < 64; off <<= 1) {
        int t = __shfl_up(v, off);
        if (lane >= off) v += t;
    }
    int ex = __shfl_up(v, 1);
    if (lane == 0) ex = 0;
    if (lane < nb) bs[lane] = ex;
}

__global__ void scan3_kernel(const int* __restrict__ local_ex, const int* __restrict__ bs,
                             const int* __restrict__ cnt,
                             int* __restrict__ rowptr, float* __restrict__ dinv) {
    int i = blockIdx.x * blockDim.x + threadIdx.x;
    if (i < NN) {
        rowptr[i] = local_ex[i] + bs[i >> 10];
        int d = cnt[i];
        dinv[i] = (d > 0) ? 1.0f / (float)d : 0.0f;
    }
    if (i == 0) rowptr[NN] = NE;
}

__global__ void fill_kernel(const int* __restrict__ src, const int* __restrict__ dst,
                            const int* __restrict__ rowptr, int* __restrict__ cursor,
                            int* __restrict__ eidx) {
    int e = blockIdx.x * blockDim.x + threadIdx.x;
    if (e < NE) {
        int d = dst[e];
        int p = rowptr[d] + atomicAdd(&cursor[d], 1);
        __builtin_nontemporal_store(src[e], &eidx[p]);  // scattered 4B: skip write-allocate
    }
}

// ---------------- weight split (all 3 layers) ----------------

__global__ void wsplit_kernel(const float* __restrict__ Ws0, const float* __restrict__ Wn0,
                              const float* __restrict__ Ws1, const float* __restrict__ Wn1,
                              const float* __restrict__ Ws2, const float* __restrict__ Wn2,
                              unsigned short* __restrict__ hi, unsigned short* __restrict__ lo) {
    int idx = blockIdx.x * blockDim.x + threadIdx.x;  // 3*128*256
    int l = idx >> 15;
    int r = idx & 32767;
    int j = r >> 8, k = r & 255;
    const float* Ws = (l == 0) ? Ws0 : (l == 1) ? Ws1 : Ws2;
    const float* Wn = (l == 0) ? Wn0 : (l == 1) ? Wn1 : Wn2;
    float v = (k < 128) ? Ws[j * 128 + k] : Wn[j * 128 + (k - 128)];
    unsigned short h = f2bf_rn(v);
    hi[idx] = h;
    lo[idx] = f2bf_rn(v - bf2f(h));
}

// ---------------- x split: [b][n][f] fp32 -> [n][b][f] hi/lo bf16 ----------------

__global__ void xsplit_kernel(const float* __restrict__ x,
                              unsigned short* __restrict__ hi, unsigned short* __restrict__ lo) {
    size_t idx = (size_t)blockIdx.x * blockDim.x + threadIdx.x;  // NB*NN*F/4 threads
    float4 v = *reinterpret_cast<const float4*>(&x[idx * 4]);
    int f4 = (int)(idx & 31);                 // F/4 = 32 float4s per row
    size_t row = idx >> 5;                    // b*NN + n
    int b = (row >= NN) ? 1 : 0;
    size_t n = row - (size_t)b * NN;
    size_t o = ((n << 1) + b) * F + f4 * 4;   // interleaved row n*2+b
    u16x4 h4, l4;
    float vv[4] = {v.x, v.y, v.z, v.w};
#pragma unroll
    for (int i = 0; i < 4; ++i) {
        unsigned short h = f2bf_rn(vv[i]);
        h4[i] = h;
        l4[i] = f2bf_rn(vv[i] - bf2f(h));
    }
    *reinterpret_cast<u16x4*>(&hi[o]) = h4;
    *reinterpret_cast<u16x4*>(&lo[o]) = l4;
}

// ---------------- mean aggregation: 1 wave/node, both batches per edge ----------------

__global__ void aggregate_bf16(const unsigned short* __restrict__ h,
                               const int* __restrict__ rowptr, const int* __restrict__ eidx,
                               const float* __restrict__ dinv,
                               unsigned short* __restrict__ agg_hi, unsigned short* __restrict__ agg_lo) {
    int gtid = blockIdx.x * blockDim.x + threadIdx.x;
    int node = gtid >> 6;
    int lane = gtid & 63;
    if (node >= NN) return;
    int g = lane >> 5, li = lane & 31;
    int s0 = rowptr[node], s1 = rowptr[node + 1];

    float acc[8] = {0.f, 0.f, 0.f, 0.f, 0.f, 0.f, 0.f, 0.f};

    for (int e = s0; e < s1; e += 8) {
        int sidx[4];
        u16x8 vv[4];
#pragma unroll
        for (int j = 0; j < 4; ++j) {
            int ee = e + 2 * j + g;
            sidx[j] = (ee < s1) ? eidx[ee] : -1;
        }
#pragma unroll
        for (int j = 0; j < 4; ++j)
            if (sidx[j] >= 0)
                vv[j] = *reinterpret_cast<const u16x8*>(&h[(size_t)sidx[j] * 256 + li * 8]);
#pragma unroll
        for (int j = 0; j < 4; ++j)
            if (sidx[j] >= 0) {
#pragma unroll
                for (int i = 0; i < 8; ++i) acc[i] += bf2f(vv[j][i]);
            }
    }

#pragma unroll
    for (int i = 0; i < 8; ++i) acc[i] += __shfl_xor(acc[i], 32);

    if (g == 0) {
        float di = dinv[node];
        u16x8 h8, l8;
#pragma unroll
        for (int i = 0; i < 8; ++i) {
            float v = acc[i] * di;
            unsigned short hh = f2bf_rn(v);
            h8[i] = hh;
            l8[i] = f2bf_rn(v - bf2f(hh));
        }
        *reinterpret_cast<u16x8*>(&agg_hi[(size_t)node * 256 + li * 8]) = h8;
        *reinterpret_cast<u16x8*>(&agg_lo[(size_t)node * 256 + li * 8]) = l8;
    }
}

// ---------------- MFMA GEMM via global_load_lds double-buffered staging ----------------
// Block: 128 rows x 128 cols, 4 waves 2x2 (wave tile 64x64, 4x4 frags of 16x16x32).
// Per K-step (32 elems): stage A-chunk (hi/lo) + W-chunk (hi/lo) = 32KB via 32x
// global_load_lds dwordx4 (fire-and-forget, deep vmcnt pipeline), double-buffered.
// LDS linear dest; the global SOURCE is pre-swizzled (granule kg = slot ^ ((row>>1)&3))
// so ds_read_b128 fragments hit 8 banks x 2 lanes (2-way = free). 64KB LDS -> 2 blk/CU.

__global__ __launch_bounds__(256) void sage_gemm_mfma(
    const unsigned short* __restrict__ Shi, const unsigned short* __restrict__ Slo,
    const unsigned short* __restrict__ Ghi, const unsigned short* __restrict__ Glo,
    const unsigned short* __restrict__ Whi, const unsigned short* __restrict__ Wlo,
    const float* __restrict__ bias,
    float* __restrict__ outf, unsigned short* __restrict__ ohi, unsigned short* __restrict__ olo,
    int final_layer)
{
    __shared__ unsigned short lds[2][4][4096];  // [buf][Ahi,Alo,Whi,Wlo][8KB]

    int tid = threadIdx.x;
    int lane = tid & 63, wave = tid >> 6;
    int wm = wave >> 1, wn = wave & 1;
    int l15 = lane & 15, kg = lane >> 4;
    int row_base = blockIdx.x * 128;
    if (row_base > M2 - 128) row_base = M2 - 128;  // tail: overlap, identical rewrites

    int s_sub = lane >> 2;   // 0..15: row within staging instruction
    int s_g   = lane & 3;    // granule slot 0..3

    auto stage = [&](int buf, int ks) {
        const unsigned short* Ah = (ks < 4) ? Shi : Ghi;
        const unsigned short* Al = (ks < 4) ? Slo : Glo;
        int ka = (ks & 3) * 32;
        int kb = ks * 32;
#pragma unroll
        for (int jj = 0; jj < 2; ++jj) {
            int j = wave * 2 + jj;
            int r = j * 16 + s_sub;                    // row (A) / out-col (W), 0..127
            int kgs = s_g ^ ((r >> 1) & 3);            // source granule for this slot
            const unsigned short* pah = &Ah[(size_t)(row_base + r) * F + ka + kgs * 8];
            const unsigned short* pal = &Al[(size_t)(row_base + r) * F + ka + kgs * 8];
            const unsigned short* pwh = &Whi[(size_t)r * 256 + kb + kgs * 8];
            const unsigned short* pwl = &Wlo[(size_t)r * 256 + kb + kgs * 8];
            __builtin_amdgcn_global_load_lds((const __attribute__((address_space(1))) void*)pah,
                (__attribute__((address_space(3))) void*)&lds[buf][0][j * 512], 16, 0, 0);
            __builtin_amdgcn_global_load_lds((const __attribute__((address_space(1))) void*)pal,
                (__attribute__((address_space(3))) void*)&lds[buf][1][j * 512], 16, 0, 0);
            __builtin_amdgcn_global_load_lds((const __attribute__((address_space(1))) void*)pwh,
                (__attribute__((address_space(3))) void*)&lds[buf][2][j * 512], 16, 0, 0);
            __builtin_amdgcn_global_load_lds((const __attribute__((address_space(1))) void*)pwl,
                (__attribute__((address_space(3))) void*)&lds[buf][3][j * 512], 16, 0, 0);
        }
    };

    f32x4 acc[4][4];
#pragma unroll
    for (int m = 0; m < 4; ++m)
#pragma unroll
        for (int n = 0; n < 4; ++n) acc[m][n] = (f32x4){0.f, 0.f, 0.f, 0.f};

    int bcol[4];
    float bv[4];
#pragma unroll
    for (int n = 0; n < 4; ++n) {
        bcol[n] = wn * 64 + n * 16 + l15;
        bv[n] = bias[bcol[n]];
    }

    stage(0, 0);
    __syncthreads();

#pragma unroll
    for (int ks = 0; ks < 8; ++ks) {
        int buf = ks & 1;
        if (ks < 7) stage(buf ^ 1, ks + 1);

        bf16x8 ah[4], al[4], bh[4], bl[4];
#pragma unroll
        for (int m = 0; m < 4; ++m) {
            int r = wm * 64 + m * 16 + l15;
            int p = (r * 4 + (kg ^ ((r >> 1) & 3))) * 8;
            ah[m] = *reinterpret_cast<const bf16x8*>(&lds[buf][0][p]);
            al[m] = *reinterpret_cast<const bf16x8*>(&lds[buf][1][p]);
        }
#pragma unroll
        for (int n = 0; n < 4; ++n) {
            int c = wn * 64 + n * 16 + l15;
            int p = (c * 4 + (kg ^ ((c >> 1) & 3))) * 8;
            bh[n] = *reinterpret_cast<const bf16x8*>(&lds[buf][2][p]);
            bl[n] = *reinterpret_cast<const bf16x8*>(&lds[buf][3][p]);
        }

#pragma unroll
        for (int m = 0; m < 4; ++m)
#pragma unroll
            for (int n = 0; n < 4; ++n) {
                acc[m][n] = __builtin_amdgcn_mfma_f32_16x16x32_bf16(ah[m], bh[n], acc[m][n], 0, 0, 0);
                acc[m][n] = __builtin_amdgcn_mfma_f32_16x16x32_bf16(ah[m], bl[n], acc[m][n], 0, 0, 0);
                acc[m][n] = __builtin_amdgcn_mfma_f32_16x16x32_bf16(al[m], bh[n], acc[m][n], 0, 0, 0);
            }

        __syncthreads();
    }

    // epilogue: C frag col=lane&15, row=(lane>>4)*4+i
    int wrow = row_base + wm * 64;
#pragma unroll
    for (int m = 0; m < 4; ++m) {
#pragma unroll
        for (int i = 0; i < 4; ++i) {
            int r = wrow + m * 16 + kg * 4 + i;
            if (r < M2) {
#pragma unroll
                for (int n = 0; n < 4; ++n) {
                    float v = fmaxf(acc[m][n][i] + bv[n], 0.f);
                    if (final_layer) {
                        // r = node*2 + b  ->  out[b][node][col]
                        size_t off = ((size_t)(r & 1) * NN + (size_t)(r >> 1)) * F + bcol[n];
                        outf[off] = v;
                    } else {
                        size_t off = (size_t)r * F + bcol[n];
                        unsigned short hh = f2bf_rn(v);
                        ohi[off] = hh;
                        olo[off] = f2bf_rn(v - bf2f(hh));
                    }
                }
            }
        }
    }
}

// ---------------- launcher ----------------

extern "C" void kernel_launch(void* const* d_in, const int* in_sizes, int n_in,
                              void* d_out, int out_size, void* d_ws, size_t ws_size,
                              hipStream_t stream) {
    const float* x  = (const float*)d_in[0];
    const int* src  = (const int*)d_in[1];
    const int* dst  = (const int*)d_in[2];
    const float* Wp[3][2] = {
        {(const float*)d_in[3], (const float*)d_in[4]},
        {(const float*)d_in[6], (const float*)d_in[7]},
        {(const float*)d_in[9], (const float*)d_in[10]},
    };
    const float* bp[3] = {(const float*)d_in[5], (const float*)d_in[8], (const float*)d_in[11]};
    float* out = (float*)d_out;

    char* p = (char*)d_ws;
    auto alloc = [&](size_t b) -> void* {
        void* r = (void*)p;
        p += (b + 255) & ~(size_t)255;
        return r;
    };
    int* cnt      = (int*)alloc(sizeof(int) * NN);
    int* cursor   = (int*)alloc(sizeof(int) * NN);
    int* rowptr   = (int*)alloc(sizeof(int) * (NN + 1));
    int* local_ex = (int*)alloc(sizeof(int) * NN);
    int* bsums    = (int*)alloc(sizeof(int) * 64);
    int* eidx     = (int*)alloc(sizeof(int) * NE);
    float* dinv   = (float*)alloc(sizeof(float) * NN);
    unsigned short* Whi = (unsigned short*)alloc(sizeof(short) * 3 * 128 * 256);
    unsigned short* Wlo = (unsigned short*)alloc(sizeof(short) * 3 * 128 * 256);
    // interleaved feature buffers [node][batch][feat], ping-pong X <-> Y, agg G
    unsigned short* Xhi = (unsigned short*)alloc(sizeof(short) * M2 * F);
    unsigned short* Xlo = (unsigned short*)alloc(sizeof(short) * M2 * F);
    unsigned short* Yhi = (unsigned short*)alloc(sizeof(short) * M2 * F);
    unsigned short* Ylo = (unsigned short*)alloc(sizeof(short) * M2 * F);
    unsigned short* Ghi = (unsigned short*)alloc(sizeof(short) * M2 * F);
    unsigned short* Glo = (unsigned short*)alloc(sizeof(short) * M2 * F);

    hipMemsetAsync(cnt, 0, (char*)rowptr - (char*)cnt, stream);  // cnt + cursor

    count_kernel<<<(NE + 255) / 256, 256, 0, stream>>>(dst, cnt);
    const int NSB = (NN + 1023) / 1024;  // 49
    scan1_kernel<<<NSB, 1024, 0, stream>>>(cnt, local_ex, bsums);
    scan2_kernel<<<1, 64, 0, stream>>>(bsums, NSB);
    scan3_kernel<<<(NN + 255) / 256, 256, 0, stream>>>(local_ex, bsums, cnt, rowptr, dinv);
    fill_kernel<<<(NE + 255) / 256, 256, 0, stream>>>(src, dst, rowptr, cursor, eidx);

    wsplit_kernel<<<3 * 128, 256, 0, stream>>>(Wp[0][0], Wp[0][1], Wp[1][0], Wp[1][1],
                                               Wp[2][0], Wp[2][1], Whi, Wlo);

    xsplit_kernel<<<((size_t)NB * NN * F / 4) / 256, 256, 0, stream>>>(x, Xhi, Xlo);

    const int AGG_BLOCKS  = (NN * 64) / 256;        // 12500
    const int GEMM_BLOCKS = (M2 + 127) / 128;       // 782

    // layer 1: X -> Y
    aggregate_bf16<<<AGG_BLOCKS, 256, 0, stream>>>(Xhi, rowptr, eidx, dinv, Ghi, Glo);
    sage_gemm_mfma<<<GEMM_BLOCKS, 256, 0, stream>>>(Xhi, Xlo, Ghi, Glo,
                                                    Whi + 0 * 32768, Wlo + 0 * 32768, bp[0],
                                                    nullptr, Yhi, Ylo, 0);
    // layer 2: Y -> X
    aggregate_bf16<<<AGG_BLOCKS, 256, 0, stream>>>(Yhi, rowptr, eidx, dinv, Ghi, Glo);
    sage_gemm_mfma<<<GEMM_BLOCKS, 256, 0, stream>>>(Yhi, Ylo, Ghi, Glo,
                                                    Whi + 1 * 32768, Wlo + 1 * 32768, bp[1],
                                                    nullptr, Xhi, Xlo, 0);
    // layer 3: X -> out
    aggregate_bf16<<<AGG_BLOCKS, 256, 0, stream>>>(Xhi, rowptr, eidx, dinv, Ghi, Glo);
    sage_gemm_mfma<<<GEMM_BLOCKS, 256, 0, stream>>>(Xhi, Xlo, Ghi, Glo,
                                                    Whi + 2 * 32768, Wlo + 2 * 32768, bp[2],
                                                    out, nullptr, nullptr, 1);
}

// Round 9
// 394.992 us; speedup vs baseline: 1.3690x; 1.0407x over previous
//
#include <hip/hip_runtime.h>

#define NN 50000
#define NE 800000
#define F  128
#define NB 2
#define M2 (NB * NN)   // 100000 fused rows, layout [node][batch][feat]

typedef __attribute__((ext_vector_type(8))) short     bf16x8;
typedef __attribute__((ext_vector_type(4))) float     f32x4;
typedef __attribute__((ext_vector_type(8))) unsigned short u16x8;
typedef __attribute__((ext_vector_type(4))) unsigned short u16x4;

__device__ inline unsigned short f2bf_rn(float f) {
    unsigned u = __float_as_uint(f);
    u += 0x7FFFu + ((u >> 16) & 1u);
    return (unsigned short)(u >> 16);
}
__device__ inline float bf2f(unsigned short h) {
    return __uint_as_float(((unsigned)h) << 16);
}

// ---------------- CSR build ----------------

__global__ void count_kernel(const int* __restrict__ dst, int* __restrict__ cnt) {
    int e = blockIdx.x * blockDim.x + threadIdx.x;
    if (e < NE) atomicAdd(&cnt[dst[e]], 1);
}

__global__ __launch_bounds__(1024) void scan1_kernel(const int* __restrict__ cnt,
                                                     int* __restrict__ local_ex,
                                                     int* __restrict__ blocksums) {
    __shared__ int sd[1024];
    int i = blockIdx.x * 1024 + threadIdx.x;
    int v = (i < NN) ? cnt[i] : 0;
    sd[threadIdx.x] = v;
    __syncthreads();
    for (int off = 1; off < 1024; off <<= 1) {
        int t = 0;
        if ((int)threadIdx.x >= off) t = sd[threadIdx.x - off];
        __syncthreads();
        sd[threadIdx.x] += t;
        __syncthreads();
    }
    if (i < NN) local_ex[i] = sd[threadIdx.x] - v;  // exclusive within block
    if (threadIdx.x == 1023) blocksums[blockIdx.x] = sd[1023];
}

__global__ void scan2_kernel(int* __restrict__ bs, int nb) {
    int lane = threadIdx.x;
    int v = (lane < nb) ? bs[lane] : 0;
    for (int off = 1; off < 64; off <<= 1) {
        int t = __shfl_up(v, off);
        if (lane >= off) v += t;
    }
    int ex = __shfl_up(v, 1);
    if (lane == 0) ex = 0;
    if (lane < nb) bs[lane] = ex;
}

__global__ void scan3_kernel(const int* __restrict__ local_ex, const int* __restrict__ bs,
                             const int* __restrict__ cnt,
                             int* __restrict__ rowptr, float* __restrict__ dinv) {
    int i = blockIdx.x * blockDim.x + threadIdx.x;
    if (i < NN) {
        rowptr[i] = local_ex[i] + bs[i >> 10];
        int d = cnt[i];
        dinv[i] = (d > 0) ? 1.0f / (float)d : 0.0f;
    }
    if (i == 0) rowptr[NN] = NE;
}

__global__ void fill_kernel(const int* __restrict__ src, const int* __restrict__ dst,
                            const int* __restrict__ rowptr, int* __restrict__ cursor,
                            unsigned short* __restrict__ eidx) {
    int e = blockIdx.x * blockDim.x + threadIdx.x;
    if (e < NE) {
        int d = dst[e];
        int p = rowptr[d] + atomicAdd(&cursor[d], 1);
        eidx[p] = (unsigned short)src[e];   // src < 50000 < 65536; u16 halves dirty lines
    }
}

// ---------------- weight split (all 3 layers) ----------------

__global__ void wsplit_kernel(const float* __restrict__ Ws0, const float* __restrict__ Wn0,
                              const float* __restrict__ Ws1, const float* __restrict__ Wn1,
                              const float* __restrict__ Ws2, const float* __restrict__ Wn2,
                              unsigned short* __restrict__ hi, unsigned short* __restrict__ lo) {
    int idx = blockIdx.x * blockDim.x + threadIdx.x;  // 3*128*256
    int l = idx >> 15;
    int r = idx & 32767;
    int j = r >> 8, k = r & 255;
    const float* Ws = (l == 0) ? Ws0 : (l == 1) ? Ws1 : Ws2;
    const float* Wn = (l == 0) ? Wn0 : (l == 1) ? Wn1 : Wn2;
    float v = (k < 128) ? Ws[j * 128 + k] : Wn[j * 128 + (k - 128)];
    unsigned short h = f2bf_rn(v);
    hi[idx] = h;
    lo[idx] = f2bf_rn(v - bf2f(h));
}

// ---------------- x split: [b][n][f] fp32 -> [n][b][f] hi/lo bf16 ----------------

__global__ void xsplit_kernel(const float* __restrict__ x,
                              unsigned short* __restrict__ hi, unsigned short* __restrict__ lo) {
    size_t idx = (size_t)blockIdx.x * blockDim.x + threadIdx.x;  // NB*NN*F/4 threads
    float4 v = *reinterpret_cast<const float4*>(&x[idx * 4]);
    int f4 = (int)(idx & 31);                 // F/4 = 32 float4s per row
    size_t row = idx >> 5;                    // b*NN + n
    int b = (row >= NN) ? 1 : 0;
    size_t n = row - (size_t)b * NN;
    size_t o = ((n << 1) + b) * F + f4 * 4;   // interleaved row n*2+b
    u16x4 h4, l4;
    float vv[4] = {v.x, v.y, v.z, v.w};
#pragma unroll
    for (int i = 0; i < 4; ++i) {
        unsigned short h = f2bf_rn(vv[i]);
        h4[i] = h;
        l4[i] = f2bf_rn(vv[i] - bf2f(h));
    }
    *reinterpret_cast<u16x4*>(&hi[o]) = h4;
    *reinterpret_cast<u16x4*>(&lo[o]) = l4;
}

// ---------------- mean aggregation: 1 wave/node, both batches per edge ----------------

__global__ void aggregate_bf16(const unsigned short* __restrict__ h,
                               const int* __restrict__ rowptr, const unsigned short* __restrict__ eidx,
                               const float* __restrict__ dinv,
                               unsigned short* __restrict__ agg_hi, unsigned short* __restrict__ agg_lo) {
    int gtid = blockIdx.x * blockDim.x + threadIdx.x;
    int node = gtid >> 6;
    int lane = gtid & 63;
    if (node >= NN) return;
    int g = lane >> 5, li = lane & 31;
    int s0 = rowptr[node], s1 = rowptr[node + 1];

    float acc[8] = {0.f, 0.f, 0.f, 0.f, 0.f, 0.f, 0.f, 0.f};

    for (int e = s0; e < s1; e += 8) {
        int sidx[4];
        u16x8 vv[4];
#pragma unroll
        for (int j = 0; j < 4; ++j) {
            int ee = e + 2 * j + g;
            sidx[j] = (ee < s1) ? (int)eidx[ee] : -1;
        }
#pragma unroll
        for (int j = 0; j < 4; ++j)
            if (sidx[j] >= 0)
                vv[j] = *reinterpret_cast<const u16x8*>(&h[(size_t)sidx[j] * 256 + li * 8]);
#pragma unroll
        for (int j = 0; j < 4; ++j)
            if (sidx[j] >= 0) {
#pragma unroll
                for (int i = 0; i < 8; ++i) acc[i] += bf2f(vv[j][i]);
            }
    }

#pragma unroll
    for (int i = 0; i < 8; ++i) acc[i] += __shfl_xor(acc[i], 32);

    if (g == 0) {
        float di = dinv[node];
        u16x8 h8, l8;
#pragma unroll
        for (int i = 0; i < 8; ++i) {
            float v = acc[i] * di;
            unsigned short hh = f2bf_rn(v);
            h8[i] = hh;
            l8[i] = f2bf_rn(v - bf2f(hh));
        }
        *reinterpret_cast<u16x8*>(&agg_hi[(size_t)node * 256 + li * 8]) = h8;
        *reinterpret_cast<u16x8*>(&agg_lo[(size_t)node * 256 + li * 8]) = l8;
    }
}

// ---------------- MFMA GEMM via global_load_lds double-buffered staging ----------------
// Block: 128 rows x 128 cols, 4 waves 2x2 (wave tile 64x64, 4x4 frags of 16x16x32).
// Per K-step (32 elems): stage A-chunk (hi/lo) + W-chunk (hi/lo) = 32KB via 32x
// global_load_lds dwordx4 (fire-and-forget, deep vmcnt pipeline), double-buffered.
// LDS linear dest; the global SOURCE is pre-swizzled (granule kg = slot ^ ((row>>1)&3))
// so ds_read_b128 fragments hit 8 banks x 2 lanes (2-way = free). 64KB LDS -> 2 blk/CU.

__global__ __launch_bounds__(256) void sage_gemm_mfma(
    const unsigned short* __restrict__ Shi, const unsigned short* __restrict__ Slo,
    const unsigned short* __restrict__ Ghi, const unsigned short* __restrict__ Glo,
    const unsigned short* __restrict__ Whi, const unsigned short* __restrict__ Wlo,
    const float* __restrict__ bias,
    float* __restrict__ outf, unsigned short* __restrict__ ohi, unsigned short* __restrict__ olo,
    int final_layer)
{
    __shared__ unsigned short lds[2][4][4096];  // [buf][Ahi,Alo,Whi,Wlo][8KB]

    int tid = threadIdx.x;
    int lane = tid & 63, wave = tid >> 6;
    int wm = wave >> 1, wn = wave & 1;
    int l15 = lane & 15, kg = lane >> 4;
    int row_base = blockIdx.x * 128;
    if (row_base > M2 - 128) row_base = M2 - 128;  // tail: overlap, identical rewrites

    int s_sub = lane >> 2;   // 0..15: row within staging instruction
    int s_g   = lane & 3;    // granule slot 0..3

    auto stage = [&](int buf, int ks) {
        const unsigned short* Ah = (ks < 4) ? Shi : Ghi;
        const unsigned short* Al = (ks < 4) ? Slo : Glo;
        int ka = (ks & 3) * 32;
        int kb = ks * 32;
#pragma unroll
        for (int jj = 0; jj < 2; ++jj) {
            int j = wave * 2 + jj;
            int r = j * 16 + s_sub;                    // row (A) / out-col (W), 0..127
            int kgs = s_g ^ ((r >> 1) & 3);            // source granule for this slot
            const unsigned short* pah = &Ah[(size_t)(row_base + r) * F + ka + kgs * 8];
            const unsigned short* pal = &Al[(size_t)(row_base + r) * F + ka + kgs * 8];
            const unsigned short* pwh = &Whi[(size_t)r * 256 + kb + kgs * 8];
            const unsigned short* pwl = &Wlo[(size_t)r * 256 + kb + kgs * 8];
            __builtin_amdgcn_global_load_lds((const __attribute__((address_space(1))) void*)pah,
                (__attribute__((address_space(3))) void*)&lds[buf][0][j * 512], 16, 0, 0);
            __builtin_amdgcn_global_load_lds((const __attribute__((address_space(1))) void*)pal,
                (__attribute__((address_space(3))) void*)&lds[buf][1][j * 512], 16, 0, 0);
            __builtin_amdgcn_global_load_lds((const __attribute__((address_space(1))) void*)pwh,
                (__attribute__((address_space(3))) void*)&lds[buf][2][j * 512], 16, 0, 0);
            __builtin_amdgcn_global_load_lds((const __attribute__((address_space(1))) void*)pwl,
                (__attribute__((address_space(3))) void*)&lds[buf][3][j * 512], 16, 0, 0);
        }
    };

    f32x4 acc[4][4];
#pragma unroll
    for (int m = 0; m < 4; ++m)
#pragma unroll
        for (int n = 0; n < 4; ++n) acc[m][n] = (f32x4){0.f, 0.f, 0.f, 0.f};

    int bcol[4];
    float bv[4];
#pragma unroll
    for (int n = 0; n < 4; ++n) {
        bcol[n] = wn * 64 + n * 16 + l15;
        bv[n] = bias[bcol[n]];
    }

    stage(0, 0);
    __syncthreads();

#pragma unroll
    for (int ks = 0; ks < 8; ++ks) {
        int buf = ks & 1;
        if (ks < 7) stage(buf ^ 1, ks + 1);

        bf16x8 ah[4], al[4], bh[4], bl[4];
#pragma unroll
        for (int m = 0; m < 4; ++m) {
            int r = wm * 64 + m * 16 + l15;
            int p = (r * 4 + (kg ^ ((r >> 1) & 3))) * 8;
            ah[m] = *reinterpret_cast<const bf16x8*>(&lds[buf][0][p]);
            al[m] = *reinterpret_cast<const bf16x8*>(&lds[buf][1][p]);
        }
#pragma unroll
        for (int n = 0; n < 4; ++n) {
            int c = wn * 64 + n * 16 + l15;
            int p = (c * 4 + (kg ^ ((c >> 1) & 3))) * 8;
            bh[n] = *reinterpret_cast<const bf16x8*>(&lds[buf][2][p]);
            bl[n] = *reinterpret_cast<const bf16x8*>(&lds[buf][3][p]);
        }

#pragma unroll
        for (int m = 0; m < 4; ++m)
#pragma unroll
            for (int n = 0; n < 4; ++n) {
                acc[m][n] = __builtin_amdgcn_mfma_f32_16x16x32_bf16(ah[m], bh[n], acc[m][n], 0, 0, 0);
                acc[m][n] = __builtin_amdgcn_mfma_f32_16x16x32_bf16(ah[m], bl[n], acc[m][n], 0, 0, 0);
                acc[m][n] = __builtin_amdgcn_mfma_f32_16x16x32_bf16(al[m], bh[n], acc[m][n], 0, 0, 0);
            }

        __syncthreads();
    }

    // epilogue: C frag col=lane&15, row=(lane>>4)*4+i
    int wrow = row_base + wm * 64;
#pragma unroll
    for (int m = 0; m < 4; ++m) {
#pragma unroll
        for (int i = 0; i < 4; ++i) {
            int r = wrow + m * 16 + kg * 4 + i;
            if (r < M2) {
#pragma unroll
                for (int n = 0; n < 4; ++n) {
                    float v = fmaxf(acc[m][n][i] + bv[n], 0.f);
                    if (final_layer) {
                        // r = node*2 + b  ->  out[b][node][col]
                        size_t off = ((size_t)(r & 1) * NN + (size_t)(r >> 1)) * F + bcol[n];
                        outf[off] = v;
                    } else {
                        size_t off = (size_t)r * F + bcol[n];
                        unsigned short hh = f2bf_rn(v);
                        ohi[off] = hh;
                        olo[off] = f2bf_rn(v - bf2f(hh));
                    }
                }
            }
        }
    }
}

// ---------------- launcher ----------------

extern "C" void kernel_launch(void* const* d_in, const int* in_sizes, int n_in,
                              void* d_out, int out_size, void* d_ws, size_t ws_size,
                              hipStream_t stream) {
    const float* x  = (const float*)d_in[0];
    const int* src  = (const int*)d_in[1];
    const int* dst  = (const int*)d_in[2];
    const float* Wp[3][2] = {
        {(const float*)d_in[3], (const float*)d_in[4]},
        {(const float*)d_in[6], (const float*)d_in[7]},
        {(const float*)d_in[9], (const float*)d_in[10]},
    };
    const float* bp[3] = {(const float*)d_in[5], (const float*)d_in[8], (const float*)d_in[11]};
    float* out = (float*)d_out;

    char* p = (char*)d_ws;
    auto alloc = [&](size_t b) -> void* {
        void* r = (void*)p;
        p += (b + 255) & ~(size_t)255;
        return r;
    };
    int* cnt      = (int*)alloc(sizeof(int) * NN);
    int* cursor   = (int*)alloc(sizeof(int) * NN);
    int* rowptr   = (int*)alloc(sizeof(int) * (NN + 1));
    int* local_ex = (int*)alloc(sizeof(int) * NN);
    int* bsums    = (int*)alloc(sizeof(int) * 64);
    unsigned short* eidx = (unsigned short*)alloc(sizeof(short) * NE);
    float* dinv   = (float*)alloc(sizeof(float) * NN);
    unsigned short* Whi = (unsigned short*)alloc(sizeof(short) * 3 * 128 * 256);
    unsigned short* Wlo = (unsigned short*)alloc(sizeof(short) * 3 * 128 * 256);
    // interleaved feature buffers [node][batch][feat], ping-pong X <-> Y, agg G
    unsigned short* Xhi = (unsigned short*)alloc(sizeof(short) * M2 * F);
    unsigned short* Xlo = (unsigned short*)alloc(sizeof(short) * M2 * F);
    unsigned short* Yhi = (unsigned short*)alloc(sizeof(short) * M2 * F);
    unsigned short* Ylo = (unsigned short*)alloc(sizeof(short) * M2 * F);
    unsigned short* Ghi = (unsigned short*)alloc(sizeof(short) * M2 * F);
    unsigned short* Glo = (unsigned short*)alloc(sizeof(short) * M2 * F);

    hipMemsetAsync(cnt, 0, (char*)rowptr - (char*)cnt, stream);  // cnt + cursor

    count_kernel<<<(NE + 255) / 256, 256, 0, stream>>>(dst, cnt);
    const int NSB = (NN + 1023) / 1024;  // 49
    scan1_kernel<<<NSB, 1024, 0, stream>>>(cnt, local_ex, bsums);
    scan2_kernel<<<1, 64, 0, stream>>>(bsums, NSB);
    scan3_kernel<<<(NN + 255) / 256, 256, 0, stream>>>(local_ex, bsums, cnt, rowptr, dinv);
    fill_kernel<<<(NE + 255) / 256, 256, 0, stream>>>(src, dst, rowptr, cursor, eidx);

    wsplit_kernel<<<3 * 128, 256, 0, stream>>>(Wp[0][0], Wp[0][1], Wp[1][0], Wp[1][1],
                                               Wp[2][0], Wp[2][1], Whi, Wlo);

    xsplit_kernel<<<((size_t)NB * NN * F / 4) / 256, 256, 0, stream>>>(x, Xhi, Xlo);

    const int AGG_BLOCKS  = (NN * 64) / 256;        // 12500
    const int GEMM_BLOCKS = (M2 + 127) / 128;       // 782

    // layer 1: X -> Y
    aggregate_bf16<<<AGG_BLOCKS, 256, 0, stream>>>(Xhi, rowptr, eidx, dinv, Ghi, Glo);
    sage_gemm_mfma<<<GEMM_BLOCKS, 256, 0, stream>>>(Xhi, Xlo, Ghi, Glo,
                                                    Whi + 0 * 32768, Wlo + 0 * 32768, bp[0],
                                                    nullptr, Yhi, Ylo, 0);
    // layer 2: Y -> X
    aggregate_bf16<<<AGG_BLOCKS, 256, 0, stream>>>(Yhi, rowptr, eidx, dinv, Ghi, Glo);
    sage_gemm_mfma<<<GEMM_BLOCKS, 256, 0, stream>>>(Yhi, Ylo, Ghi, Glo,
                                                    Whi + 1 * 32768, Wlo + 1 * 32768, bp[1],
                                                    nullptr, Xhi, Xlo, 0);
    // layer 3: X -> out
    aggregate_bf16<<<AGG_BLOCKS, 256, 0, stream>>>(Xhi, rowptr, eidx, dinv, Ghi, Glo);
    sage_gemm_mfma<<<GEMM_BLOCKS, 256, 0, stream>>>(Xhi, Xlo, Ghi, Glo,
                                                    Whi + 2 * 32768, Wlo + 2 * 32768, bp[2],
                                                    out, nullptr, nullptr, 1);
}

// Round 10
// 352.242 us; speedup vs baseline: 1.5352x; 1.1214x over previous
//
#include <hip/hip_runtime.h>

#define NN 50000
#define NE 800000
#define F  128
#define NB 2
#define M2 (NB * NN)   // 100000 fused rows, layout [node][batch][feat]

typedef __attribute__((ext_vector_type(8))) short     bf16x8;
typedef __attribute__((ext_vector_type(4))) float     f32x4;
typedef __attribute__((ext_vector_type(8))) unsigned short u16x8;
typedef __attribute__((ext_vector_type(4))) unsigned short u16x4;

__device__ inline unsigned short f2bf_rn(float f) {
    unsigned u = __float_as_uint(f);
    u += 0x7FFFu + ((u >> 16) & 1u);
    return (unsigned short)(u >> 16);
}
__device__ inline float bf2f(unsigned short h) {
    return __uint_as_float(((unsigned)h) << 16);
}

// ---------------- CSR build ----------------

__global__ void count_kernel(const int* __restrict__ dst, int* __restrict__ cnt) {
    int e = blockIdx.x * blockDim.x + threadIdx.x;
    if (e < NE) atomicAdd(&cnt[dst[e]], 1);
}

__global__ __launch_bounds__(1024) void scan1_kernel(const int* __restrict__ cnt,
                                                     int* __restrict__ local_ex,
                                                     int* __restrict__ blocksums) {
    __shared__ int sd[1024];
    int i = blockIdx.x * 1024 + threadIdx.x;
    int v = (i < NN) ? cnt[i] : 0;
    sd[threadIdx.x] = v;
    __syncthreads();
    for (int off = 1; off < 1024; off <<= 1) {
        int t = 0;
        if ((int)threadIdx.x >= off) t = sd[threadIdx.x - off];
        __syncthreads();
        sd[threadIdx.x] += t;
        __syncthreads();
    }
    if (i < NN) local_ex[i] = sd[threadIdx.x] - v;  // exclusive within block
    if (threadIdx.x == 1023) blocksums[blockIdx.x] = sd[1023];
}

__global__ void scan2_kernel(int* __restrict__ bs, int nb) {
    int lane = threadIdx.x;
    int v = (lane < nb) ? bs[lane] : 0;
    for (int off = 1; off < 64; off <<= 1) {
        int t = __shfl_up(v, off);
        if (lane >= off) v += t;
    }
    int ex = __shfl_up(v, 1);
    if (lane == 0) ex = 0;
    if (lane < nb) bs[lane] = ex;
}

__global__ void scan3_kernel(const int* __restrict__ local_ex, const int* __restrict__ bs,
                             const int* __restrict__ cnt,
                             int* __restrict__ rowptr, float* __restrict__ dinv) {
    int i = blockIdx.x * blockDim.x + threadIdx.x;
    if (i < NN) {
        rowptr[i] = local_ex[i] + bs[i >> 10];
        int d = cnt[i];
        dinv[i] = (d > 0) ? 1.0f / (float)d : 0.0f;
    }
    if (i == 0) rowptr[NN] = NE;
}

__global__ void fill_kernel(const int* __restrict__ src, const int* __restrict__ dst,
                            const int* __restrict__ rowptr, int* __restrict__ cursor,
                            unsigned short* __restrict__ eidx) {
    int e = blockIdx.x * blockDim.x + threadIdx.x;
    if (e < NE) {
        int d = dst[e];
        int p = rowptr[d] + atomicAdd(&cursor[d], 1);
        eidx[p] = (unsigned short)src[e];   // src < 50000 < 65536
    }
}

// ---------------- weight split (all 3 layers) ----------------

__global__ void wsplit_kernel(const float* __restrict__ Ws0, const float* __restrict__ Wn0,
                              const float* __restrict__ Ws1, const float* __restrict__ Wn1,
                              const float* __restrict__ Ws2, const float* __restrict__ Wn2,
                              unsigned short* __restrict__ hi, unsigned short* __restrict__ lo) {
    int idx = blockIdx.x * blockDim.x + threadIdx.x;  // 3*128*256
    int l = idx >> 15;
    int r = idx & 32767;
    int j = r >> 8, k = r & 255;
    const float* Ws = (l == 0) ? Ws0 : (l == 1) ? Ws1 : Ws2;
    const float* Wn = (l == 0) ? Wn0 : (l == 1) ? Wn1 : Wn2;
    float v = (k < 128) ? Ws[j * 128 + k] : Wn[j * 128 + (k - 128)];
    unsigned short h = f2bf_rn(v);
    hi[idx] = h;
    lo[idx] = f2bf_rn(v - bf2f(h));
}

// ---------------- x split: [b][n][f] fp32 -> [n][b][f] hi/lo bf16 ----------------

__global__ void xsplit_kernel(const float* __restrict__ x,
                              unsigned short* __restrict__ hi, unsigned short* __restrict__ lo) {
    size_t idx = (size_t)blockIdx.x * blockDim.x + threadIdx.x;  // NB*NN*F/4 threads
    float4 v = *reinterpret_cast<const float4*>(&x[idx * 4]);
    int f4 = (int)(idx & 31);                 // F/4 = 32 float4s per row
    size_t row = idx >> 5;                    // b*NN + n
    int b = (row >= NN) ? 1 : 0;
    size_t n = row - (size_t)b * NN;
    size_t o = ((n << 1) + b) * F + f4 * 4;   // interleaved row n*2+b
    u16x4 h4, l4;
    float vv[4] = {v.x, v.y, v.z, v.w};
#pragma unroll
    for (int i = 0; i < 4; ++i) {
        unsigned short h = f2bf_rn(vv[i]);
        h4[i] = h;
        l4[i] = f2bf_rn(vv[i] - bf2f(h));
    }
    *reinterpret_cast<u16x4*>(&hi[o]) = h4;
    *reinterpret_cast<u16x4*>(&lo[o]) = l4;
}

// ---------------- mean aggregation: 1 wave/node, both batches per edge ----------------
// Output: bf16 hi ONLY (the gather input is already bf16-rounded; an exact hi/lo
// split of an inexact sum wastes half the write+reread bytes).

__global__ void aggregate_bf16(const unsigned short* __restrict__ h,
                               const int* __restrict__ rowptr, const unsigned short* __restrict__ eidx,
                               const float* __restrict__ dinv,
                               unsigned short* __restrict__ agg_hi) {
    int gtid = blockIdx.x * blockDim.x + threadIdx.x;
    int node = gtid >> 6;
    int lane = gtid & 63;
    if (node >= NN) return;
    int g = lane >> 5, li = lane & 31;
    int s0 = rowptr[node], s1 = rowptr[node + 1];

    float acc[8] = {0.f, 0.f, 0.f, 0.f, 0.f, 0.f, 0.f, 0.f};

    for (int e = s0; e < s1; e += 8) {
        int sidx[4];
        u16x8 vv[4];
#pragma unroll
        for (int j = 0; j < 4; ++j) {
            int ee = e + 2 * j + g;
            sidx[j] = (ee < s1) ? (int)eidx[ee] : -1;
        }
#pragma unroll
        for (int j = 0; j < 4; ++j)
            if (sidx[j] >= 0)
                vv[j] = *reinterpret_cast<const u16x8*>(&h[(size_t)sidx[j] * 256 + li * 8]);
#pragma unroll
        for (int j = 0; j < 4; ++j)
            if (sidx[j] >= 0) {
#pragma unroll
                for (int i = 0; i < 8; ++i) acc[i] += bf2f(vv[j][i]);
            }
    }

#pragma unroll
    for (int i = 0; i < 8; ++i) acc[i] += __shfl_xor(acc[i], 32);

    if (g == 0) {
        float di = dinv[node];
        u16x8 h8;
#pragma unroll
        for (int i = 0; i < 8; ++i) h8[i] = f2bf_rn(acc[i] * di);
        *reinterpret_cast<u16x8*>(&agg_hi[(size_t)node * 256 + li * 8]) = h8;
    }
}

// ---------------- MFMA GEMM via global_load_lds double-buffered staging ----------------
// Block: 128 rows x 128 cols, 4 waves 2x2 (wave tile 64x64, 4x4 frags of 16x16x32).
// Streams: [0]=A-hi (S for ks<4, G for ks>=4), [1]=W-hi, [2]=W-lo, [3]=S-lo (SELF_LO only).
// SELF_LO=1 (layer 1, fp32 input needs hi/lo): 64KB LDS, 2 blk/CU.
// SELF_LO=0 (layers 2-3, h is bf16-hi only):   48KB LDS, 3 blk/CU.
// LDS linear dest; global SOURCE pre-swizzled (granule ^= (row>>1)&3) => 2-way reads (free).

template<int SELF_LO>
__global__ __launch_bounds__(256) void sage_gemm_mfma(
    const unsigned short* __restrict__ Shi, const unsigned short* __restrict__ Slo,
    const unsigned short* __restrict__ Ghi,
    const unsigned short* __restrict__ Whi, const unsigned short* __restrict__ Wlo,
    const float* __restrict__ bias,
    float* __restrict__ outf, unsigned short* __restrict__ ohi,
    int final_layer)
{
    __shared__ unsigned short lds[2][3 + SELF_LO][4096];

    int tid = threadIdx.x;
    int lane = tid & 63, wave = tid >> 6;
    int wm = wave >> 1, wn = wave & 1;
    int l15 = lane & 15, kg = lane >> 4;
    int row_base = blockIdx.x * 128;
    if (row_base > M2 - 128) row_base = M2 - 128;  // tail: overlap, identical rewrites

    int s_sub = lane >> 2;   // 0..15: row within staging instruction
    int s_g   = lane & 3;    // granule slot 0..3

    auto stage = [&](int buf, int ks) {
        const unsigned short* Ah = (ks < 4) ? Shi : Ghi;
        int ka = (ks & 3) * 32;
        int kb = ks * 32;
#pragma unroll
        for (int jj = 0; jj < 2; ++jj) {
            int j = wave * 2 + jj;
            int r = j * 16 + s_sub;                    // row (A) / out-col (W), 0..127
            int kgs = s_g ^ ((r >> 1) & 3);            // source granule for this slot
            const unsigned short* pah = &Ah[(size_t)(row_base + r) * F + ka + kgs * 8];
            const unsigned short* pwh = &Whi[(size_t)r * 256 + kb + kgs * 8];
            const unsigned short* pwl = &Wlo[(size_t)r * 256 + kb + kgs * 8];
            __builtin_amdgcn_global_load_lds((const __attribute__((address_space(1))) void*)pah,
                (__attribute__((address_space(3))) void*)&lds[buf][0][j * 512], 16, 0, 0);
            __builtin_amdgcn_global_load_lds((const __attribute__((address_space(1))) void*)pwh,
                (__attribute__((address_space(3))) void*)&lds[buf][1][j * 512], 16, 0, 0);
            __builtin_amdgcn_global_load_lds((const __attribute__((address_space(1))) void*)pwl,
                (__attribute__((address_space(3))) void*)&lds[buf][2][j * 512], 16, 0, 0);
            if (SELF_LO && ks < 4) {
                const unsigned short* pal = &Slo[(size_t)(row_base + r) * F + ka + kgs * 8];
                __builtin_amdgcn_global_load_lds((const __attribute__((address_space(1))) void*)pal,
                    (__attribute__((address_space(3))) void*)&lds[buf][3][j * 512], 16, 0, 0);
            }
        }
    };

    f32x4 acc[4][4];
#pragma unroll
    for (int m = 0; m < 4; ++m)
#pragma unroll
        for (int n = 0; n < 4; ++n) acc[m][n] = (f32x4){0.f, 0.f, 0.f, 0.f};

    int bcol[4];
    float bv[4];
#pragma unroll
    for (int n = 0; n < 4; ++n) {
        bcol[n] = wn * 64 + n * 16 + l15;
        bv[n] = bias[bcol[n]];
    }

    stage(0, 0);
    __syncthreads();

#pragma unroll
    for (int ks = 0; ks < 8; ++ks) {
        int buf = ks & 1;
        if (ks < 7) stage(buf ^ 1, ks + 1);

        bf16x8 ah[4], al[4], bh[4], bl[4];
#pragma unroll
        for (int m = 0; m < 4; ++m) {
            int r = wm * 64 + m * 16 + l15;
            int p = (r * 4 + (kg ^ ((r >> 1) & 3))) * 8;
            ah[m] = *reinterpret_cast<const bf16x8*>(&lds[buf][0][p]);
            if (SELF_LO && ks < 4)
                al[m] = *reinterpret_cast<const bf16x8*>(&lds[buf][3][p]);
        }
#pragma unroll
        for (int n = 0; n < 4; ++n) {
            int c = wn * 64 + n * 16 + l15;
            int p = (c * 4 + (kg ^ ((c >> 1) & 3))) * 8;
            bh[n] = *reinterpret_cast<const bf16x8*>(&lds[buf][1][p]);
            bl[n] = *reinterpret_cast<const bf16x8*>(&lds[buf][2][p]);
        }

#pragma unroll
        for (int m = 0; m < 4; ++m)
#pragma unroll
            for (int n = 0; n < 4; ++n) {
                acc[m][n] = __builtin_amdgcn_mfma_f32_16x16x32_bf16(ah[m], bh[n], acc[m][n], 0, 0, 0);
                acc[m][n] = __builtin_amdgcn_mfma_f32_16x16x32_bf16(ah[m], bl[n], acc[m][n], 0, 0, 0);
                if (SELF_LO && ks < 4)
                    acc[m][n] = __builtin_amdgcn_mfma_f32_16x16x32_bf16(al[m], bh[n], acc[m][n], 0, 0, 0);
            }

        __syncthreads();
    }

    // epilogue: C frag col=lane&15, row=(lane>>4)*4+i
    int wrow = row_base + wm * 64;
#pragma unroll
    for (int m = 0; m < 4; ++m) {
#pragma unroll
        for (int i = 0; i < 4; ++i) {
            int r = wrow + m * 16 + kg * 4 + i;
            if (r < M2) {
#pragma unroll
                for (int n = 0; n < 4; ++n) {
                    float v = fmaxf(acc[m][n][i] + bv[n], 0.f);
                    if (final_layer) {
                        // r = node*2 + b  ->  out[b][node][col]
                        size_t off = ((size_t)(r & 1) * NN + (size_t)(r >> 1)) * F + bcol[n];
                        outf[off] = v;
                    } else {
                        size_t off = (size_t)r * F + bcol[n];
                        ohi[off] = f2bf_rn(v);
                    }
                }
            }
        }
    }
}

// ---------------- launcher ----------------

extern "C" void kernel_launch(void* const* d_in, const int* in_sizes, int n_in,
                              void* d_out, int out_size, void* d_ws, size_t ws_size,
                              hipStream_t stream) {
    const float* x  = (const float*)d_in[0];
    const int* src  = (const int*)d_in[1];
    const int* dst  = (const int*)d_in[2];
    const float* Wp[3][2] = {
        {(const float*)d_in[3], (const float*)d_in[4]},
        {(const float*)d_in[6], (const float*)d_in[7]},
        {(const float*)d_in[9], (const float*)d_in[10]},
    };
    const float* bp[3] = {(const float*)d_in[5], (const float*)d_in[8], (const float*)d_in[11]};
    float* out = (float*)d_out;

    char* p = (char*)d_ws;
    auto alloc = [&](size_t b) -> void* {
        void* r = (void*)p;
        p += (b + 255) & ~(size_t)255;
        return r;
    };
    int* cnt      = (int*)alloc(sizeof(int) * NN);
    int* cursor   = (int*)alloc(sizeof(int) * NN);
    int* rowptr   = (int*)alloc(sizeof(int) * (NN + 1));
    int* local_ex = (int*)alloc(sizeof(int) * NN);
    int* bsums    = (int*)alloc(sizeof(int) * 64);
    unsigned short* eidx = (unsigned short*)alloc(sizeof(short) * NE);
    float* dinv   = (float*)alloc(sizeof(float) * NN);
    unsigned short* Whi = (unsigned short*)alloc(sizeof(short) * 3 * 128 * 256);
    unsigned short* Wlo = (unsigned short*)alloc(sizeof(short) * 3 * 128 * 256);
    // interleaved [node][batch][feat]: layer-1 input hi/lo; intermediates hi-only; agg hi-only
    unsigned short* X0hi = (unsigned short*)alloc(sizeof(short) * M2 * F);
    unsigned short* X0lo = (unsigned short*)alloc(sizeof(short) * M2 * F);
    unsigned short* H1   = (unsigned short*)alloc(sizeof(short) * M2 * F);
    unsigned short* H2   = (unsigned short*)alloc(sizeof(short) * M2 * F);
    unsigned short* Ghi  = (unsigned short*)alloc(sizeof(short) * M2 * F);

    hipMemsetAsync(cnt, 0, (char*)rowptr - (char*)cnt, stream);  // cnt + cursor

    count_kernel<<<(NE + 255) / 256, 256, 0, stream>>>(dst, cnt);
    const int NSB = (NN + 1023) / 1024;  // 49
    scan1_kernel<<<NSB, 1024, 0, stream>>>(cnt, local_ex, bsums);
    scan2_kernel<<<1, 64, 0, stream>>>(bsums, NSB);
    scan3_kernel<<<(NN + 255) / 256, 256, 0, stream>>>(local_ex, bsums, cnt, rowptr, dinv);
    fill_kernel<<<(NE + 255) / 256, 256, 0, stream>>>(src, dst, rowptr, cursor, eidx);

    wsplit_kernel<<<3 * 128, 256, 0, stream>>>(Wp[0][0], Wp[0][1], Wp[1][0], Wp[1][1],
                                               Wp[2][0], Wp[2][1], Whi, Wlo);

    xsplit_kernel<<<((size_t)NB * NN * F / 4) / 256, 256, 0, stream>>>(x, X0hi, X0lo);

    const int AGG_BLOCKS  = (NN * 64) / 256;        // 12500
    const int GEMM_BLOCKS = (M2 + 127) / 128;       // 782

    // layer 1: X0 -> H1 (self hi/lo, agg hi)
    aggregate_bf16<<<AGG_BLOCKS, 256, 0, stream>>>(X0hi, rowptr, eidx, dinv, Ghi);
    sage_gemm_mfma<1><<<GEMM_BLOCKS, 256, 0, stream>>>(X0hi, X0lo, Ghi,
                                                       Whi + 0 * 32768, Wlo + 0 * 32768, bp[0],
                                                       nullptr, H1, 0);
    // layer 2: H1 -> H2 (self hi, agg hi)
    aggregate_bf16<<<AGG_BLOCKS, 256, 0, stream>>>(H1, rowptr, eidx, dinv, Ghi);
    sage_gemm_mfma<0><<<GEMM_BLOCKS, 256, 0, stream>>>(H1, nullptr, Ghi,
                                                       Whi + 1 * 32768, Wlo + 1 * 32768, bp[1],
                                                       nullptr, H2, 0);
    // layer 3: H2 -> out (fp32)
    aggregate_bf16<<<AGG_BLOCKS, 256, 0, stream>>>(H2, rowptr, eidx, dinv, Ghi);
    sage_gemm_mfma<0><<<GEMM_BLOCKS, 256, 0, stream>>>(H2, nullptr, Ghi,
                                                       Whi + 2 * 32768, Wlo + 2 * 32768, bp[2],
                                                       out, nullptr, 1);
}